// Round 1
// baseline (929.235 us; speedup 1.0000x reference)
//
#include <hip/hip_runtime.h>

#define NN 50000
#define NE 500000
#define DD 128

// ---------------------------------------------------------------------------
// Workspace layout (floats):
//   [0, NN)            deg -> dinv (in place)
//   [NN, NN+NN*128)    xw
//   then int32 src[NE], dst[NE]
// ---------------------------------------------------------------------------

// Normalize edge_index (int32 or int64 on the wire) into int32 src/dst.
__global__ void k_convert(const int* __restrict__ ei, int* __restrict__ src,
                          int* __restrict__ dst, int e) {
    int i = blockIdx.x * blockDim.x + threadIdx.x;
    if (i >= e) return;
    // int64 little-endian with values < 2^31 -> every odd int32 word is 0.
    bool is64 = (ei[1] == 0) & (ei[3] == 0) & (ei[5] == 0) & (ei[7] == 0);
    if (is64) {
        src[i] = ei[2 * i];
        dst[i] = ei[2 * (e + i)];
    } else {
        src[i] = ei[i];
        dst[i] = ei[e + i];
    }
}

__global__ void k_deg_init(float* __restrict__ deg, int n) {
    int i = blockIdx.x * blockDim.x + threadIdx.x;
    if (i < n) deg[i] = 1.0f;  // self-loop
}

__global__ void k_deg_edges(const int* __restrict__ dst, float* __restrict__ deg, int e) {
    int i = blockIdx.x * blockDim.x + threadIdx.x;
    if (i < e) atomicAdd(&deg[dst[i]], 1.0f);
}

__global__ void k_dinv(float* __restrict__ deg, int n) {
    int i = blockIdx.x * blockDim.x + threadIdx.x;
    if (i < n) deg[i] = rsqrtf(deg[i]);  // deg >= 1 always (self-loops)
}

// xw = x @ W; out = xw * dinv^2 (self-loop contribution, fully initializes out)
__global__ __launch_bounds__(256, 2) void k_gemm(
    const float* __restrict__ x, const float* __restrict__ W,
    const float* __restrict__ dinv, float* __restrict__ xw,
    float* __restrict__ out, int n) {
    __shared__ float Ws[128 * 128];  // 64 KB
    __shared__ float Xs[32 * 128];   // 16 KB
    const int t = threadIdx.x;
    const int row0 = blockIdx.x * 32;

    // Load W (16384 floats = 4096 float4; 16 per thread)
#pragma unroll
    for (int i = 0; i < 16; ++i) {
        int idx = (i * 256 + t) * 4;
        *(float4*)&Ws[idx] = *(const float4*)&W[idx];
    }
    // Load X tile (4096 floats = 1024 float4; 4 per thread)
#pragma unroll
    for (int i = 0; i < 4; ++i) {
        int idx = (i * 256 + t) * 4;
        int r = idx >> 7, c = idx & 127;
        int gr = row0 + r;
        float4 v = make_float4(0.f, 0.f, 0.f, 0.f);
        if (gr < n) v = *(const float4*)&x[gr * DD + c];
        *(float4*)&Xs[idx] = v;
    }
    __syncthreads();

    const int colg = (t & 31) * 4;   // 4 output cols
    const int rg   = (t >> 5) * 4;   // 4 output rows
    float acc[4][4] = {};
#pragma unroll 4
    for (int k = 0; k < 128; ++k) {
        float4 wv = *(const float4*)&Ws[k * DD + colg];
#pragma unroll
        for (int i = 0; i < 4; ++i) {
            float xv = Xs[(rg + i) * DD + k];
            acc[i][0] = fmaf(xv, wv.x, acc[i][0]);
            acc[i][1] = fmaf(xv, wv.y, acc[i][1]);
            acc[i][2] = fmaf(xv, wv.z, acc[i][2]);
            acc[i][3] = fmaf(xv, wv.w, acc[i][3]);
        }
    }
#pragma unroll
    for (int i = 0; i < 4; ++i) {
        int gr = row0 + rg + i;
        if (gr < n) {
            float s = dinv[gr];
            s = s * s;
            float4 v = make_float4(acc[i][0], acc[i][1], acc[i][2], acc[i][3]);
            *(float4*)&xw[gr * DD + colg] = v;
            float4 o = make_float4(v.x * s, v.y * s, v.z * s, v.w * s);
            *(float4*)&out[gr * DD + colg] = o;
        }
    }
}

// One 32-lane group per edge: gather xw[src], scale, atomic scatter to out[dst].
__global__ __launch_bounds__(256) void k_scatter(
    const int* __restrict__ src, const int* __restrict__ dst,
    const float* __restrict__ dinv, const float* __restrict__ xw,
    float* __restrict__ out, int e) {
    int g = blockIdx.x * blockDim.x + threadIdx.x;
    int lane = g & 31;
    int edge = g >> 5;
    if (edge >= e) return;
    int s = src[edge], d = dst[edge];
    float norm = dinv[s] * dinv[d];
    float4 v = *(const float4*)&xw[s * DD + lane * 4];
    float* op = &out[d * DD + lane * 4];
    atomicAdd(op + 0, v.x * norm);
    atomicAdd(op + 1, v.y * norm);
    atomicAdd(op + 2, v.z * norm);
    atomicAdd(op + 3, v.w * norm);
}

__global__ void k_final(float* __restrict__ out, const float* __restrict__ b, int n4) {
    int i = blockIdx.x * blockDim.x + threadIdx.x;
    if (i >= n4) return;
    float4 v = ((float4*)out)[i];
    float4 bb = *(const float4*)&b[(i & 31) * 4];
    v.x = fmaxf(v.x + bb.x, 0.f);
    v.y = fmaxf(v.y + bb.y, 0.f);
    v.z = fmaxf(v.z + bb.z, 0.f);
    v.w = fmaxf(v.w + bb.w, 0.f);
    ((float4*)out)[i] = v;
}

extern "C" void kernel_launch(void* const* d_in, const int* in_sizes, int n_in,
                              void* d_out, int out_size, void* d_ws, size_t ws_size,
                              hipStream_t stream) {
    const float* x  = (const float*)d_in[0];
    const int*   ei = (const int*)d_in[1];
    const float* W  = (const float*)d_in[2];
    const float* b  = (const float*)d_in[3];
    float* out = (float*)d_out;

    float* wsf  = (float*)d_ws;
    float* deg  = wsf;                     // NN floats (deg -> dinv in place)
    float* xw   = wsf + NN;                // NN*DD floats
    int*   srcW = (int*)(wsf + NN + NN * DD);
    int*   dstW = srcW + NE;

    k_convert<<<(NE + 255) / 256, 256, 0, stream>>>(ei, srcW, dstW, NE);
    k_deg_init<<<(NN + 255) / 256, 256, 0, stream>>>(deg, NN);
    k_deg_edges<<<(NE + 255) / 256, 256, 0, stream>>>(dstW, deg, NE);
    k_dinv<<<(NN + 255) / 256, 256, 0, stream>>>(deg, NN);
    k_gemm<<<(NN + 31) / 32, 256, 0, stream>>>(x, W, deg, xw, out, NN);
    k_scatter<<<(NE * 32 + 255) / 256, 256, 0, stream>>>(srcW, dstW, deg, xw, out, NE);
    k_final<<<(NN * DD / 4 + 255) / 256, 256, 0, stream>>>(out, b, NN * DD / 4);
}

// Round 2
// 151.937 us; speedup vs baseline: 6.1159x; 6.1159x over previous
//
#include <hip/hip_runtime.h>

#define NN 50000
#define NE 500000
#define DD 128

// ---------------------------------------------------------------------------
// Math: xs[n] = (x@W)[n] * dinv[n]
//       out[d] = relu( dinv[d] * (xs[d] + sum_{edges e: dst=d} xs[src_e]) + b )
// CSR built by counting sort on dst. deg[d] = hist[d] + 1 (self-loop).
// ---------------------------------------------------------------------------

// Normalize edge_index (int32 or int64 on the wire) into int32 src/dst.
__global__ void k_convert(const int* __restrict__ ei, int* __restrict__ src,
                          int* __restrict__ dst, int e) {
    int i = blockIdx.x * blockDim.x + threadIdx.x;
    if (i >= e) return;
    bool is64 = (ei[1] == 0) & (ei[3] == 0) & (ei[5] == 0) & (ei[7] == 0);
    if (is64) {
        src[i] = ei[2 * i];
        dst[i] = ei[2 * (e + i)];
    } else {
        src[i] = ei[i];
        dst[i] = ei[e + i];
    }
}

__global__ void k_zero(int* __restrict__ p, int n) {
    int i = blockIdx.x * blockDim.x + threadIdx.x;
    if (i < n) p[i] = 0;
}

__global__ void k_hist(const int* __restrict__ dst, int* __restrict__ cnt, int e) {
    int i = blockIdx.x * blockDim.x + threadIdx.x;
    if (i < e) atomicAdd(&cnt[dst[i]], 1);
}

__global__ void k_dinv(const int* __restrict__ cnt, float* __restrict__ dinv, int n) {
    int i = blockIdx.x * blockDim.x + threadIdx.x;
    if (i < n) dinv[i] = rsqrtf((float)cnt[i] + 1.0f);  // +1 self-loop
}

// --- exclusive scan of cnt[0..n) into rowptr, 1024 elems per block ---
__global__ void k_scan1(const int* __restrict__ cnt, int* __restrict__ rowptr,
                        int* __restrict__ bsum, int n) {
    __shared__ int ts[256];
    int t = threadIdx.x;
    int base = blockIdx.x * 1024 + t * 4;
    int v[4];
    int s = 0;
#pragma unroll
    for (int i = 0; i < 4; ++i) {
        int idx = base + i;
        v[i] = (idx < n) ? cnt[idx] : 0;
        s += v[i];
    }
    ts[t] = s;
    __syncthreads();
    for (int off = 1; off < 256; off <<= 1) {
        int x = (t >= off) ? ts[t - off] : 0;
        __syncthreads();
        ts[t] += x;
        __syncthreads();
    }
    if (t == 255) bsum[blockIdx.x] = ts[255];
    int run = ts[t] - s;  // exclusive prefix for this thread's chunk
#pragma unroll
    for (int i = 0; i < 4; ++i) {
        int idx = base + i;
        if (idx < n) rowptr[idx] = run;
        run += v[i];
    }
}

__global__ void k_scan2(int* __restrict__ bsum, int nb) {
    __shared__ int ts[64];
    int t = threadIdx.x;
    int v = (t < nb) ? bsum[t] : 0;
    ts[t] = v;
    __syncthreads();
    for (int off = 1; off < 64; off <<= 1) {
        int x = (t >= off) ? ts[t - off] : 0;
        __syncthreads();
        ts[t] += x;
        __syncthreads();
    }
    if (t < nb) bsum[t] = ts[t] - v;  // exclusive
}

__global__ void k_scan3(int* __restrict__ rowptr, const int* __restrict__ bsum,
                        int* __restrict__ cursor, int n, int e) {
    int i = blockIdx.x * blockDim.x + threadIdx.x;
    if (i < n) {
        int r = rowptr[i] + bsum[i >> 10];
        rowptr[i] = r;
        cursor[i] = r;
    }
    if (i == n) rowptr[n] = e;
}

// Scatter edges into CSR order: col[pos] = src, segment of dst.
__global__ void k_esort(const int* __restrict__ src, const int* __restrict__ dst,
                        int* __restrict__ cursor, int* __restrict__ col, int e) {
    int i = blockIdx.x * blockDim.x + threadIdx.x;
    if (i >= e) return;
    int pos = atomicAdd(&cursor[dst[i]], 1);
    col[pos] = src[i];
}

// xs = (x @ W) * dinv[row]
__global__ __launch_bounds__(256, 2) void k_gemm(
    const float* __restrict__ x, const float* __restrict__ W,
    const float* __restrict__ dinv, float* __restrict__ xs, int n) {
    __shared__ float Ws[128 * 128];  // 64 KB
    __shared__ float Xs[32 * 128];   // 16 KB
    const int t = threadIdx.x;
    const int row0 = blockIdx.x * 32;

#pragma unroll
    for (int i = 0; i < 16; ++i) {
        int idx = (i * 256 + t) * 4;
        *(float4*)&Ws[idx] = *(const float4*)&W[idx];
    }
#pragma unroll
    for (int i = 0; i < 4; ++i) {
        int idx = (i * 256 + t) * 4;
        int r = idx >> 7, c = idx & 127;
        int gr = row0 + r;
        float4 v = make_float4(0.f, 0.f, 0.f, 0.f);
        if (gr < n) v = *(const float4*)&x[gr * DD + c];
        *(float4*)&Xs[idx] = v;
    }
    __syncthreads();

    const int colg = (t & 31) * 4;
    const int rg   = (t >> 5) * 4;
    float acc[4][4] = {};
#pragma unroll 4
    for (int k = 0; k < 128; ++k) {
        float4 wv = *(const float4*)&Ws[k * DD + colg];
#pragma unroll
        for (int i = 0; i < 4; ++i) {
            float xv = Xs[(rg + i) * DD + k];
            acc[i][0] = fmaf(xv, wv.x, acc[i][0]);
            acc[i][1] = fmaf(xv, wv.y, acc[i][1]);
            acc[i][2] = fmaf(xv, wv.z, acc[i][2]);
            acc[i][3] = fmaf(xv, wv.w, acc[i][3]);
        }
    }
#pragma unroll
    for (int i = 0; i < 4; ++i) {
        int gr = row0 + rg + i;
        if (gr < n) {
            float s = dinv[gr];
            float4 v = make_float4(acc[i][0] * s, acc[i][1] * s,
                                   acc[i][2] * s, acc[i][3] * s);
            *(float4*)&xs[gr * DD + colg] = v;
        }
    }
}

// One 64-lane wave per dst node; lane owns 2 feature dims (float2).
__global__ __launch_bounds__(256) void k_aggr(
    const int* __restrict__ rowptr, const int* __restrict__ col,
    const float* __restrict__ xs, const float* __restrict__ dinv,
    const float* __restrict__ b, float* __restrict__ out) {
    int wid = (blockIdx.x * blockDim.x + threadIdx.x) >> 6;
    int lane = threadIdx.x & 63;
    if (wid >= NN) return;
    int beg = rowptr[wid], end = rowptr[wid + 1];
    const int c = lane * 2;
    float2 acc = *(const float2*)&xs[wid * DD + c];  // self-loop term
    int j = beg;
    for (; j + 4 <= end; j += 4) {
        int s0 = col[j], s1 = col[j + 1], s2 = col[j + 2], s3 = col[j + 3];
        float2 a0 = *(const float2*)&xs[s0 * DD + c];
        float2 a1 = *(const float2*)&xs[s1 * DD + c];
        float2 a2 = *(const float2*)&xs[s2 * DD + c];
        float2 a3 = *(const float2*)&xs[s3 * DD + c];
        acc.x += (a0.x + a1.x) + (a2.x + a3.x);
        acc.y += (a0.y + a1.y) + (a2.y + a3.y);
    }
    for (; j < end; ++j) {
        int s = col[j];
        float2 a = *(const float2*)&xs[s * DD + c];
        acc.x += a.x;
        acc.y += a.y;
    }
    float dv = dinv[wid];
    float2 bb = *(const float2*)&b[c];
    float ox = fmaxf(fmaf(acc.x, dv, bb.x), 0.f);
    float oy = fmaxf(fmaf(acc.y, dv, bb.y), 0.f);
    *(float2*)&out[wid * DD + c] = make_float2(ox, oy);
}

extern "C" void kernel_launch(void* const* d_in, const int* in_sizes, int n_in,
                              void* d_out, int out_size, void* d_ws, size_t ws_size,
                              hipStream_t stream) {
    const float* x  = (const float*)d_in[0];
    const int*   ei = (const int*)d_in[1];
    const float* W  = (const float*)d_in[2];
    const float* b  = (const float*)d_in[3];
    float* out = (float*)d_out;

    // Workspace layout
    char* p = (char*)d_ws;
    float* dinv   = (float*)p;            p += NN * sizeof(float);
    float* xs     = (float*)p;            p += (size_t)NN * DD * sizeof(float);
    int*   srcW   = (int*)p;              p += NE * sizeof(int);
    int*   dstW   = (int*)p;              p += NE * sizeof(int);
    int*   colW   = (int*)p;              p += NE * sizeof(int);
    int*   cnt    = (int*)p;              p += NN * sizeof(int);
    int*   rowptr = (int*)p;              p += (NN + 1) * sizeof(int);
    int*   cursor = (int*)p;              p += NN * sizeof(int);
    int*   bsum   = (int*)p;              p += 64 * sizeof(int);

    const int nb256_e = (NE + 255) / 256;
    const int nb256_n = (NN + 255) / 256;
    const int nscan   = (NN + 1023) / 1024;  // 49

    k_convert<<<nb256_e, 256, 0, stream>>>(ei, srcW, dstW, NE);
    k_zero<<<nb256_n, 256, 0, stream>>>(cnt, NN);
    k_hist<<<nb256_e, 256, 0, stream>>>(dstW, cnt, NE);
    k_dinv<<<nb256_n, 256, 0, stream>>>(cnt, dinv, NN);
    k_scan1<<<nscan, 256, 0, stream>>>(cnt, rowptr, bsum, NN);
    k_scan2<<<1, 64, 0, stream>>>(bsum, nscan);
    k_scan3<<<(NN + 256) / 256, 256, 0, stream>>>(rowptr, bsum, cursor, NN, NE);
    k_esort<<<nb256_e, 256, 0, stream>>>(srcW, dstW, cursor, colW, NE);
    k_gemm<<<(NN + 31) / 32, 256, 0, stream>>>(x, W, dinv, xs, NN);
    k_aggr<<<(NN * 64 + 255) / 256, 256, 0, stream>>>(rowptr, colW, xs, dinv, b, out);
}

// Round 3
// 131.972 us; speedup vs baseline: 7.0411x; 1.1513x over previous
//
#include <hip/hip_runtime.h>

#define NN 50000
#define NE 500000
#define DD 128

// ---------------------------------------------------------------------------
// Math: xs[n] = bf16( (x@W)[n] * dinv[n] )          (12.8 MB gather table)
//       out[d] = relu( dinv[d] * (xs[d] + sum_{e: dst=d} xs[src_e]) + b )
// CSR built by counting sort on dst. deg[d] = hist[d] + 1 (self-loop).
// ---------------------------------------------------------------------------

__device__ __forceinline__ unsigned int bf16pair(float a, float b) {
    unsigned int ua = __float_as_uint(a);
    ua = (ua + 0x7FFFu + ((ua >> 16) & 1u)) >> 16;   // RNE
    unsigned int ub = __float_as_uint(b);
    ub = (ub + 0x7FFFu + ((ub >> 16) & 1u)) >> 16;
    return ua | (ub << 16);
}

// Normalize edge_index (int32 or int64) into int32 src/dst + dst histogram.
__global__ void k_convert_hist(const int* __restrict__ ei, int* __restrict__ src,
                               int* __restrict__ dst, int* __restrict__ cnt, int e) {
    int i = blockIdx.x * blockDim.x + threadIdx.x;
    if (i >= e) return;
    bool is64 = (ei[1] == 0) & (ei[3] == 0) & (ei[5] == 0) & (ei[7] == 0);
    int s, d;
    if (is64) {
        s = ei[2 * i];
        d = ei[2 * (e + i)];
    } else {
        s = ei[i];
        d = ei[e + i];
    }
    src[i] = s;
    dst[i] = d;
    atomicAdd(&cnt[d], 1);
}

// exclusive scan of cnt (1024/block) + dinv = rsqrt(cnt+1)
__global__ void k_scan1(const int* __restrict__ cnt, int* __restrict__ rowptr,
                        int* __restrict__ bsum, float* __restrict__ dinv, int n) {
    __shared__ int ts[256];
    int t = threadIdx.x;
    int base = blockIdx.x * 1024 + t * 4;
    int v[4];
    int s = 0;
#pragma unroll
    for (int i = 0; i < 4; ++i) {
        int idx = base + i;
        v[i] = (idx < n) ? cnt[idx] : 0;
        if (idx < n) dinv[idx] = rsqrtf((float)v[i] + 1.0f);
        s += v[i];
    }
    ts[t] = s;
    __syncthreads();
    for (int off = 1; off < 256; off <<= 1) {
        int x = (t >= off) ? ts[t - off] : 0;
        __syncthreads();
        ts[t] += x;
        __syncthreads();
    }
    if (t == 255) bsum[blockIdx.x] = ts[255];
    int run = ts[t] - s;
#pragma unroll
    for (int i = 0; i < 4; ++i) {
        int idx = base + i;
        if (idx < n) rowptr[idx] = run;
        run += v[i];
    }
}

__global__ void k_scan2(int* __restrict__ bsum, int nb) {
    __shared__ int ts[64];
    int t = threadIdx.x;
    int v = (t < nb) ? bsum[t] : 0;
    ts[t] = v;
    __syncthreads();
    for (int off = 1; off < 64; off <<= 1) {
        int x = (t >= off) ? ts[t - off] : 0;
        __syncthreads();
        ts[t] += x;
        __syncthreads();
    }
    if (t < nb) bsum[t] = ts[t] - v;
}

__global__ void k_scan3(int* __restrict__ rowptr, const int* __restrict__ bsum,
                        int* __restrict__ cursor, int n, int e) {
    int i = blockIdx.x * blockDim.x + threadIdx.x;
    if (i < n) {
        int r = rowptr[i] + bsum[i >> 10];
        rowptr[i] = r;
        cursor[i] = r;
    }
    if (i == n) rowptr[n] = e;
}

__global__ void k_esort(const int* __restrict__ src, const int* __restrict__ dst,
                        int* __restrict__ cursor, int* __restrict__ col, int e) {
    int i = blockIdx.x * blockDim.x + threadIdx.x;
    if (i >= e) return;
    int pos = atomicAdd(&cursor[dst[i]], 1);
    col[pos] = src[i];
}

// xs_bf16 = bf16( (x @ W) * dinv[row] ).  64 rows x 128 cols per block.
__global__ __launch_bounds__(256) void k_gemm(
    const float* __restrict__ x, const float* __restrict__ W,
    const float* __restrict__ dinv, unsigned int* __restrict__ xs, int n) {
    __shared__ float Ws[32 * 128];   // 16 KB (k-tile)
    __shared__ float Xs[64 * 36];    // 9 KB (pad 36 vs bank conflicts)
    const int t = threadIdx.x;
    const int row0 = blockIdx.x * 64;
    const int tc = t & 15;   // cols tc*4 .. tc*4+3  and  +64
    const int tr = t >> 4;   // rows tr*4 .. tr*4+3
    float acc[4][8] = {};

    const int xr = t >> 2, xp = t & 3;   // X staging: row, quarter (8 floats)

    for (int k0 = 0; k0 < 128; k0 += 32) {
        __syncthreads();
#pragma unroll
        for (int i = 0; i < 4; ++i) {
            int idx = i * 256 + t;          // float4 index in 32x128 tile
            int kk = idx >> 5;
            int cc = (idx & 31) * 4;
            *(float4*)&Ws[kk * 128 + cc] = *(const float4*)&W[(k0 + kk) * DD + cc];
        }
        {
            int gr = row0 + xr;
            float4 a = make_float4(0.f, 0.f, 0.f, 0.f), b2 = a;
            if (gr < n) {
                a  = *(const float4*)&x[gr * DD + k0 + xp * 8];
                b2 = *(const float4*)&x[gr * DD + k0 + xp * 8 + 4];
            }
            *(float4*)&Xs[xr * 36 + xp * 8]     = a;
            *(float4*)&Xs[xr * 36 + xp * 8 + 4] = b2;
        }
        __syncthreads();

#pragma unroll
        for (int k = 0; k < 32; ++k) {
            float4 w0 = *(const float4*)&Ws[k * 128 + tc * 4];
            float4 w1 = *(const float4*)&Ws[k * 128 + tc * 4 + 64];
            float xv[4];
#pragma unroll
            for (int i = 0; i < 4; ++i) xv[i] = Xs[(tr * 4 + i) * 36 + k];
#pragma unroll
            for (int i = 0; i < 4; ++i) {
                acc[i][0] = fmaf(xv[i], w0.x, acc[i][0]);
                acc[i][1] = fmaf(xv[i], w0.y, acc[i][1]);
                acc[i][2] = fmaf(xv[i], w0.z, acc[i][2]);
                acc[i][3] = fmaf(xv[i], w0.w, acc[i][3]);
                acc[i][4] = fmaf(xv[i], w1.x, acc[i][4]);
                acc[i][5] = fmaf(xv[i], w1.y, acc[i][5]);
                acc[i][6] = fmaf(xv[i], w1.z, acc[i][6]);
                acc[i][7] = fmaf(xv[i], w1.w, acc[i][7]);
            }
        }
    }

#pragma unroll
    for (int i = 0; i < 4; ++i) {
        int gr = row0 + tr * 4 + i;
        if (gr < n) {
            float dv = dinv[gr];
            unsigned int* row = xs + (size_t)gr * 64;
            row[tc * 2]      = bf16pair(acc[i][0] * dv, acc[i][1] * dv);
            row[tc * 2 + 1]  = bf16pair(acc[i][2] * dv, acc[i][3] * dv);
            row[tc * 2 + 32] = bf16pair(acc[i][4] * dv, acc[i][5] * dv);
            row[tc * 2 + 33] = bf16pair(acc[i][6] * dv, acc[i][7] * dv);
        }
    }
}

// One 64-lane wave per dst node; lane owns 2 bf16 dims (one dword per row).
__global__ __launch_bounds__(256) void k_aggr(
    const int* __restrict__ rowptr, const int* __restrict__ col,
    const unsigned int* __restrict__ xs, const float* __restrict__ dinv,
    const float* __restrict__ b, float* __restrict__ out) {
    int wid = (blockIdx.x * blockDim.x + threadIdx.x) >> 6;
    int lane = threadIdx.x & 63;
    if (wid >= NN) return;
    int beg = rowptr[wid], end = rowptr[wid + 1];
    unsigned int u = xs[(size_t)wid * 64 + lane];   // self-loop term
    float ax = __uint_as_float(u << 16);
    float ay = __uint_as_float(u & 0xFFFF0000u);
    int j = beg;
    for (; j + 4 <= end; j += 4) {
        int s0 = col[j], s1 = col[j + 1], s2 = col[j + 2], s3 = col[j + 3];
        unsigned int u0 = xs[(size_t)s0 * 64 + lane];
        unsigned int u1 = xs[(size_t)s1 * 64 + lane];
        unsigned int u2 = xs[(size_t)s2 * 64 + lane];
        unsigned int u3 = xs[(size_t)s3 * 64 + lane];
        ax += (__uint_as_float(u0 << 16) + __uint_as_float(u1 << 16)) +
              (__uint_as_float(u2 << 16) + __uint_as_float(u3 << 16));
        ay += (__uint_as_float(u0 & 0xFFFF0000u) + __uint_as_float(u1 & 0xFFFF0000u)) +
              (__uint_as_float(u2 & 0xFFFF0000u) + __uint_as_float(u3 & 0xFFFF0000u));
    }
    for (; j < end; ++j) {
        unsigned int us = xs[(size_t)col[j] * 64 + lane];
        ax += __uint_as_float(us << 16);
        ay += __uint_as_float(us & 0xFFFF0000u);
    }
    float dv = dinv[wid];
    float2 bb = *(const float2*)&b[lane * 2];
    float ox = fmaxf(fmaf(ax, dv, bb.x), 0.f);
    float oy = fmaxf(fmaf(ay, dv, bb.y), 0.f);
    *(float2*)&out[(size_t)wid * DD + lane * 2] = make_float2(ox, oy);
}

extern "C" void kernel_launch(void* const* d_in, const int* in_sizes, int n_in,
                              void* d_out, int out_size, void* d_ws, size_t ws_size,
                              hipStream_t stream) {
    const float* x  = (const float*)d_in[0];
    const int*   ei = (const int*)d_in[1];
    const float* W  = (const float*)d_in[2];
    const float* b  = (const float*)d_in[3];
    float* out = (float*)d_out;

    char* p = (char*)d_ws;
    float*        dinv   = (float*)p;        p += NN * sizeof(float);
    unsigned int* xs     = (unsigned int*)p; p += (size_t)NN * 64 * sizeof(unsigned int);
    int*          srcW   = (int*)p;          p += NE * sizeof(int);
    int*          dstW   = (int*)p;          p += NE * sizeof(int);
    int*          colW   = (int*)p;          p += NE * sizeof(int);
    int*          cnt    = (int*)p;          p += NN * sizeof(int);
    int*          rowptr = (int*)p;          p += (NN + 1) * sizeof(int);
    int*          cursor = (int*)p;          p += NN * sizeof(int);
    int*          bsum   = (int*)p;          p += 64 * sizeof(int);

    const int nb256_e = (NE + 255) / 256;
    const int nscan   = (NN + 1023) / 1024;  // 49

    hipMemsetAsync(cnt, 0, NN * sizeof(int), stream);
    k_convert_hist<<<nb256_e, 256, 0, stream>>>(ei, srcW, dstW, cnt, NE);
    k_scan1<<<nscan, 256, 0, stream>>>(cnt, rowptr, bsum, dinv, NN);
    k_scan2<<<1, 64, 0, stream>>>(bsum, nscan);
    k_scan3<<<(NN + 256) / 256, 256, 0, stream>>>(rowptr, bsum, cursor, NN, NE);
    k_esort<<<nb256_e, 256, 0, stream>>>(srcW, dstW, cursor, colW, NE);
    k_gemm<<<(NN + 63) / 64, 256, 0, stream>>>(x, W, dinv, xs, NN);
    k_aggr<<<(NN * 64 + 255) / 256, 256, 0, stream>>>(rowptr, colW, xs, dinv, b, out);
}

// Round 5
// 114.913 us; speedup vs baseline: 8.0864x; 1.1485x over previous
//
#include <hip/hip_runtime.h>

#define NN 50000
#define NE 500000
#define DD 128

typedef __attribute__((ext_vector_type(8))) short bf16x8;
typedef __attribute__((ext_vector_type(4))) float f32x4;

// ---------------------------------------------------------------------------
// Math: xs[n] = bf16( (x@W)[n] * dinv[n] )          (12.8 MB gather table)
//       out[d] = relu( dinv[d] * (xs[d] + sum_{e: dst=d} xs[src_e]) + b )
// CSR built by counting sort on dst. deg[d] = hist[d] + 1 (self-loop).
// GEMM via mfma_f32_16x16x32_bf16 (inputs converted to bf16 in-register).
// ---------------------------------------------------------------------------

__device__ __forceinline__ unsigned int bf16pair(float a, float b) {
    unsigned int ua = __float_as_uint(a);
    ua = (ua + 0x7FFFu + ((ua >> 16) & 1u)) >> 16;   // RNE
    unsigned int ub = __float_as_uint(b);
    ub = (ub + 0x7FFFu + ((ub >> 16) & 1u)) >> 16;
    return ua | (ub << 16);
}

__global__ void k_zero(int* __restrict__ p, int n) {
    int i = blockIdx.x * blockDim.x + threadIdx.x;
    if (i < n) p[i] = 0;
}

// Normalize edge_index (int32 or int64) into int32 src/dst + dst histogram.
__global__ void k_convert_hist(const int* __restrict__ ei, int* __restrict__ src,
                               int* __restrict__ dst, int* __restrict__ cnt, int e) {
    int i = blockIdx.x * blockDim.x + threadIdx.x;
    if (i >= e) return;
    bool is64 = (ei[1] == 0) & (ei[3] == 0) & (ei[5] == 0) & (ei[7] == 0);
    int s, d;
    if (is64) {
        s = ei[2 * i];
        d = ei[2 * (e + i)];
    } else {
        s = ei[i];
        d = ei[e + i];
    }
    src[i] = s;
    dst[i] = d;
    atomicAdd(&cnt[d], 1);
}

// exclusive scan of cnt (1024/block) + dinv = rsqrt(cnt+1)
__global__ void k_scan1(const int* __restrict__ cnt, int* __restrict__ rowptr,
                        int* __restrict__ bsum, float* __restrict__ dinv, int n) {
    __shared__ int ts[256];
    int t = threadIdx.x;
    int base = blockIdx.x * 1024 + t * 4;
    int v[4];
    int s = 0;
#pragma unroll
    for (int i = 0; i < 4; ++i) {
        int idx = base + i;
        v[i] = (idx < n) ? cnt[idx] : 0;
        if (idx < n) dinv[idx] = rsqrtf((float)v[i] + 1.0f);
        s += v[i];
    }
    ts[t] = s;
    __syncthreads();
    for (int off = 1; off < 256; off <<= 1) {
        int x = (t >= off) ? ts[t - off] : 0;
        __syncthreads();
        ts[t] += x;
        __syncthreads();
    }
    if (t == 255) bsum[blockIdx.x] = ts[255];
    int run = ts[t] - s;
#pragma unroll
    for (int i = 0; i < 4; ++i) {
        int idx = base + i;
        if (idx < n) rowptr[idx] = run;
        run += v[i];
    }
}

__global__ void k_scan2(int* __restrict__ bsum, int nb) {
    __shared__ int ts[64];
    int t = threadIdx.x;
    int v = (t < nb) ? bsum[t] : 0;
    ts[t] = v;
    __syncthreads();
    for (int off = 1; off < 64; off <<= 1) {
        int x = (t >= off) ? ts[t - off] : 0;
        __syncthreads();
        ts[t] += x;
        __syncthreads();
    }
    if (t < nb) bsum[t] = ts[t] - v;
}

__global__ void k_scan3(int* __restrict__ rowptr, const int* __restrict__ bsum,
                        int* __restrict__ cursor, int n, int e) {
    int i = blockIdx.x * blockDim.x + threadIdx.x;
    if (i < n) {
        int r = rowptr[i] + bsum[i >> 10];
        rowptr[i] = r;
        cursor[i] = r;
    }
    if (i == n) rowptr[n] = e;
}

__global__ void k_esort(const int* __restrict__ src, const int* __restrict__ dst,
                        int* __restrict__ cursor, int* __restrict__ col, int e) {
    int i = blockIdx.x * blockDim.x + threadIdx.x;
    if (i >= e) return;
    int pos = atomicAdd(&cursor[dst[i]], 1);
    col[pos] = src[i];
}

// Repack W (128x128 fp32, row-major, k-major rows) into B-fragment-linear bf16:
// for col-tile t8 (0..7), k-step s (0..3), lane l (0..63):
//   frag elem j (0..7) = W[k = s*32 + (l>>4)*8 + j][col = t8*16 + (l&15)]
// stored contiguously 16 B per (t8,s,lane).
__global__ void k_wfrag(const float* __restrict__ W, unsigned int* __restrict__ Wf) {
    int id = blockIdx.x * blockDim.x + threadIdx.x;  // 0..2047
    if (id >= 2048) return;
    int lane = id & 63;
    int ts = id >> 6;
    int t8 = ts >> 2, s = ts & 3;
    int col = t8 * 16 + (lane & 15);
    int k0 = s * 32 + (lane >> 4) * 8;
    unsigned int w[4];
#pragma unroll
    for (int j = 0; j < 4; ++j) {
        float a = W[(k0 + 2 * j) * DD + col];
        float bb = W[(k0 + 2 * j + 1) * DD + col];
        w[j] = bf16pair(a, bb);
    }
    Wf[id * 4 + 0] = w[0];
    Wf[id * 4 + 1] = w[1];
    Wf[id * 4 + 2] = w[2];
    Wf[id * 4 + 3] = w[3];
}

// xs = bf16( (x @ W) * dinv[row] ) via MFMA. 4 waves/block, 16 rows/wave.
__global__ __launch_bounds__(256) void k_gemm(
    const float* __restrict__ x, const unsigned int* __restrict__ Wf,
    const float* __restrict__ dinv, unsigned short* __restrict__ xs, int n) {
    const int t = threadIdx.x;
    const int wave = t >> 6, lane = t & 63;
    const int row0 = blockIdx.x * 64 + wave * 16;
    const int arow = min(row0 + (lane & 15), n - 1);  // clamp; stores guarded
    const int kbase = (lane >> 4) * 8;

    // A fragments for all 4 k-steps: lane holds row (lane&15), k = kbase..kbase+7
    bf16x8 af[4];
#pragma unroll
    for (int s = 0; s < 4; ++s) {
        const float* px = &x[(size_t)arow * DD + s * 32 + kbase];
        float4 a0 = *(const float4*)px;
        float4 a1 = *(const float4*)(px + 4);
        unsigned int p[4];
        p[0] = bf16pair(a0.x, a0.y);
        p[1] = bf16pair(a0.z, a0.w);
        p[2] = bf16pair(a1.x, a1.y);
        p[3] = bf16pair(a1.z, a1.w);
        af[s] = __builtin_bit_cast(bf16x8, *(f32x4*)p);
    }

    f32x4 acc[8] = {};
#pragma unroll
    for (int s = 0; s < 4; ++s) {
#pragma unroll
        for (int t8 = 0; t8 < 8; ++t8) {
            bf16x8 bf = *(const bf16x8*)&Wf[((t8 * 4 + s) * 64 + lane) * 4];
            acc[t8] = __builtin_amdgcn_mfma_f32_16x16x32_bf16(af[s], bf, acc[t8], 0, 0, 0);
        }
    }

    // C/D: col = lane&15, row = (lane>>4)*4 + i
    const int rrow0 = row0 + (lane >> 4) * 4;
    const int colb = lane & 15;
#pragma unroll
    for (int i = 0; i < 4; ++i) {
        int r = rrow0 + i;
        if (r < n) {
            float dv = dinv[r];
#pragma unroll
            for (int t8 = 0; t8 < 8; ++t8) {
                float v = acc[t8][i] * dv;
                unsigned int uv = __float_as_uint(v);
                uv = (uv + 0x7FFFu + ((uv >> 16) & 1u)) >> 16;
                xs[(size_t)r * DD + t8 * 16 + colb] = (unsigned short)uv;
            }
        }
    }
}

// One 64-lane wave per dst node; lane owns 2 bf16 dims (one dword per row).
__global__ __launch_bounds__(256) void k_aggr(
    const int* __restrict__ rowptr, const int* __restrict__ col,
    const unsigned int* __restrict__ xs, const float* __restrict__ dinv,
    const float* __restrict__ b, float* __restrict__ out) {
    int wid = (blockIdx.x * blockDim.x + threadIdx.x) >> 6;
    int lane = threadIdx.x & 63;
    if (wid >= NN) return;
    int beg = rowptr[wid], end = rowptr[wid + 1];
    unsigned int u = xs[(size_t)wid * 64 + lane];   // self-loop term
    float ax = __uint_as_float(u << 16);
    float ay = __uint_as_float(u & 0xFFFF0000u);
    int j = beg;
    for (; j + 4 <= end; j += 4) {
        int s0 = col[j], s1 = col[j + 1], s2 = col[j + 2], s3 = col[j + 3];
        unsigned int u0 = xs[(size_t)s0 * 64 + lane];
        unsigned int u1 = xs[(size_t)s1 * 64 + lane];
        unsigned int u2 = xs[(size_t)s2 * 64 + lane];
        unsigned int u3 = xs[(size_t)s3 * 64 + lane];
        ax += (__uint_as_float(u0 << 16) + __uint_as_float(u1 << 16)) +
              (__uint_as_float(u2 << 16) + __uint_as_float(u3 << 16));
        ay += (__uint_as_float(u0 & 0xFFFF0000u) + __uint_as_float(u1 & 0xFFFF0000u)) +
              (__uint_as_float(u2 & 0xFFFF0000u) + __uint_as_float(u3 & 0xFFFF0000u));
    }
    for (; j < end; ++j) {
        unsigned int us = xs[(size_t)col[j] * 64 + lane];
        ax += __uint_as_float(us << 16);
        ay += __uint_as_float(us & 0xFFFF0000u);
    }
    float dv = dinv[wid];
    float2 bb = *(const float2*)&b[lane * 2];
    float ox = fmaxf(fmaf(ax, dv, bb.x), 0.f);
    float oy = fmaxf(fmaf(ay, dv, bb.y), 0.f);
    *(float2*)&out[(size_t)wid * DD + lane * 2] = make_float2(ox, oy);
}

extern "C" void kernel_launch(void* const* d_in, const int* in_sizes, int n_in,
                              void* d_out, int out_size, void* d_ws, size_t ws_size,
                              hipStream_t stream) {
    const float* x  = (const float*)d_in[0];
    const int*   ei = (const int*)d_in[1];
    const float* W  = (const float*)d_in[2];
    const float* b  = (const float*)d_in[3];
    float* out = (float*)d_out;

    char* p = (char*)d_ws;
    float*          dinv   = (float*)p;          p += NN * sizeof(float);
    unsigned short* xs     = (unsigned short*)p; p += (size_t)NN * DD * sizeof(unsigned short);
    int*            srcW   = (int*)p;            p += NE * sizeof(int);
    int*            dstW   = (int*)p;            p += NE * sizeof(int);
    int*            colW   = (int*)p;            p += NE * sizeof(int);
    int*            cnt    = (int*)p;            p += NN * sizeof(int);
    int*            rowptr = (int*)p;            p += (NN + 1) * sizeof(int);
    int*            cursor = (int*)p;            p += NN * sizeof(int);
    int*            bsum   = (int*)p;            p += 64 * sizeof(int);
    unsigned int*   Wf     = (unsigned int*)p;   p += 2048 * 4 * sizeof(unsigned int);

    const int nb256_e = (NE + 255) / 256;
    const int nscan   = (NN + 1023) / 1024;  // 49

    k_zero<<<(NN + 255) / 256, 256, 0, stream>>>(cnt, NN);
    k_convert_hist<<<nb256_e, 256, 0, stream>>>(ei, srcW, dstW, cnt, NE);
    k_wfrag<<<8, 256, 0, stream>>>(W, Wf);
    k_scan1<<<nscan, 256, 0, stream>>>(cnt, rowptr, bsum, dinv, NN);
    k_scan2<<<1, 64, 0, stream>>>(bsum, nscan);
    k_scan3<<<(NN + 256) / 256, 256, 0, stream>>>(rowptr, bsum, cursor, NN, NE);
    k_esort<<<nb256_e, 256, 0, stream>>>(srcW, dstW, cursor, colW, NE);
    k_gemm<<<(NN + 63) / 64, 256, 0, stream>>>(x, Wf, dinv, xs, NN);
    k_aggr<<<(NN * 64 + 255) / 256, 256, 0, stream>>>(rowptr, colW,
                                                      (const unsigned int*)xs, dinv, b, out);
}